// Round 2
// baseline (80.252 us; speedup 1.0000x reference)
//
#include <hip/hip_runtime.h>
#include <stdint.h>

#define D_IN    2048
#define NT      15
#define PPT     14359      // 7*(2048+1) + 8*2
#define NVALID  60         // 15 trees * 4 used internal nodes

typedef __bf16   bf16x8 __attribute__((ext_vector_type(8)));
typedef float    f32x4  __attribute__((ext_vector_type(4)));
typedef uint32_t u32x4  __attribute__((ext_vector_type(4)));

// ---------------- prep: split W into bf16 hi/lo in MFMA-B fragment order ----
// W[n][k], n = t*4+i (nodes 4..6 never reach the output -> only 60 of 105 cols)
// frag (ks, f, part) at bytes ((ks*4+f)*2+part)*1024 + lane*16, lane=(n&15)|(((k>>3)&3)<<4)
// Also (block 0) computes per-tree bias + folded softmax/weight coefficients.
__global__ __launch_bounds__(256) void prep_split(const float* __restrict__ tp,
                                                  const float* __restrict__ tw,
                                                  unsigned short* __restrict__ bsp,
                                                  float* __restrict__ bias,
                                                  float* __restrict__ coef) {
  int id = blockIdx.x * 256 + threadIdx.x;   // [0, 64*2048)
  int n = id >> 11;
  int k = id & 2047;
  float v = 0.0f;
  if (n < NVALID) {
    int t = n >> 2, i = n & 3;
    v = tp[t * PPT + i * D_IN + k];
  }
  uint32_t u  = __float_as_uint(v);
  uint32_t hm = u & 0xFFFF0000u;             // truncated-bf16 hi (residual catches the rest)
  float    lo = v - __uint_as_float(hm);
  uint32_t lu = __float_as_uint(lo);
  int ks = k >> 5, f = n >> 4;
  int lane = (n & 15) | (((k >> 3) & 3) << 4);
  int j = k & 7;
  size_t base = ((size_t)(ks * 4 + f) * 2) * 512 + (size_t)lane * 8 + j;
  bsp[base]       = (unsigned short)(u  >> 16);   // part 0 = hi
  bsp[base + 512] = (unsigned short)(lu >> 16);   // part 1 = lo

  if (blockIdx.x == 0) {
    int tid = threadIdx.x;
    if (tid < 64) {
      float b = 0.0f;
      if (tid < NVALID) { int t = tid >> 2, i = tid & 3; b = tp[t * PPT + 14336 + i]; }
      bias[tid] = b;
    } else if (tid < 64 + NT) {
      int t = tid - 64;
      const float* ll = tp + t * PPT + 14343;  // leaf_logits [8][2]
      float d0[8], d1[8];
#pragma unroll
      for (int le = 0; le < 8; ++le) {
        float aa = ll[2 * le], bb = ll[2 * le + 1];
        float m = fmaxf(aa, bb);
        float e0 = __expf(aa - m), e1 = __expf(bb - m);
        float inv = 1.0f / (e0 + e1);
        d0[le] = e0 * inv; d1[le] = e1 * inv;
      }
      float w = tw[t];
      float* c = coef + t * 10;
      c[0] = w * (d0[0] + d0[2] + d0[4] + d0[6]);
      c[1] = w * (d1[0] + d1[2] + d1[4] + d1[6]);
      c[2] = w * (d0[1] - d0[2]);
      c[3] = w * (d1[1] - d1[2]);
      c[4] = w * (d0[3] - d0[4]);
      c[5] = w * (d1[3] - d1[4]);
      c[6] = w * (d0[5] - d0[6]);
      c[7] = w * (d1[5] - d1[6]);
      c[8] = w * d0[7];
      c[9] = w * d1[7];
    }
  }
}

// ---------------- main fused kernel ------------------------------------------
#define CVT_PAIR(P, Q, HW, LW) do {                                   \
    uint32_t _up = __float_as_uint(P), _uq = __float_as_uint(Q);      \
    uint32_t _mp = _up & 0xFFFF0000u, _mq = _uq & 0xFFFF0000u;        \
    (HW) = (_up >> 16) | _mq;                                         \
    float _lp = (P) - __uint_as_float(_mp);                           \
    float _lq = (Q) - __uint_as_float(_mq);                           \
    (LW) = (__float_as_uint(_lp) >> 16) |                             \
           (__float_as_uint(_lq) & 0xFFFF0000u);                      \
  } while (0)

__device__ __forceinline__ void cvt_hilo(const float4 A, const float4 B,
                                         bf16x8& hi, bf16x8& lo) {
  u32x4 hw, lw;
  CVT_PAIR(A.x, A.y, hw[0], lw[0]);
  CVT_PAIR(A.z, A.w, hw[1], lw[1]);
  CVT_PAIR(B.x, B.y, hw[2], lw[2]);
  CVT_PAIR(B.z, B.w, hw[3], lw[3]);
  hi = __builtin_bit_cast(bf16x8, hw);
  lo = __builtin_bit_cast(bf16x8, lw);
}

// Block = 32 rows, 4 waves. Wave w: rows (w&1)*16, K-half (w>>1).
// B fragments loaded straight from global (L2-resident, fragment-ordered) ->
// no LDS staging, no in-loop barriers, waves free-run.
__global__ __launch_bounds__(256, 4) void tree_fused(
    const float* __restrict__ x,
    const unsigned short* __restrict__ bsp,
    const float* __restrict__ bias,
    const float* __restrict__ coef,
    float* __restrict__ out)
{
  __shared__ float red[2][16][68];           // pair-reduce + transposed epilogue

  const int tid = threadIdx.x;
  const int w     = tid >> 6;
  const int l     = tid & 63;
  const int rl    = l & 15;
  const int g     = l >> 4;
  const int mrow  = w & 1;                   // which 16-row group
  const int khalf = w >> 1;                  // which K half

  const int rowTile = blockIdx.x * 32 + mrow * 16;
  const float* xbase = x + (size_t)(rowTile + rl) * D_IN + khalf * 1024 + g * 8;
  const unsigned char* bbase = (const unsigned char*)bsp + (size_t)khalf * 262144 + l * 16;

  f32x4 acc[4] = {};

  auto loadB = [&](u32x4 (&b)[8], int ksl) {
    const unsigned char* p = bbase + (size_t)ksl * 8192;
#pragma unroll
    for (int q = 0; q < 8; ++q) b[q] = *(const u32x4*)(p + q * 1024);
  };
  auto loadA = [&](float4& p0, float4& p1, int ksl) {
    const float* p = xbase + ksl * 32;
    p0 = *(const float4*)p;
    p1 = *(const float4*)(p + 4);
  };
  auto compute = [&](float4 A0, float4 A1, u32x4 (&b)[8]) {
    bf16x8 ahi, alo;
    cvt_hilo(A0, A1, ahi, alo);
#pragma unroll
    for (int f = 0; f < 4; ++f) {
      bf16x8 bh = __builtin_bit_cast(bf16x8, b[2 * f]);
      bf16x8 bl = __builtin_bit_cast(bf16x8, b[2 * f + 1]);
      acc[f] = __builtin_amdgcn_mfma_f32_16x16x32_bf16(ahi, bh, acc[f], 0, 0, 0);
      acc[f] = __builtin_amdgcn_mfma_f32_16x16x32_bf16(alo, bh, acc[f], 0, 0, 0);
      acc[f] = __builtin_amdgcn_mfma_f32_16x16x32_bf16(ahi, bl, acc[f], 0, 0, 0);
    }
  };

  u32x4 bA[8], bB[8];
  float4 a0A, a1A, a0B, a1B;
  loadB(bA, 0);
  loadA(a0A, a1A, 0);

#pragma unroll
  for (int kk = 0; kk < 16; ++kk) {
    const int k1 = 2 * kk + 1;
    const int k2 = (2 * kk + 2 < 32) ? 2 * kk + 2 : 31;   // clamp (redundant tail load)
    loadB(bB, k1);
    loadA(a0B, a1B, k1);
    compute(a0A, a1A, bA);
    loadB(bA, k2);
    loadA(a0A, a1A, k2);
    compute(a0B, a1B, bB);
  }

  // ---- pair reduction: khalf=1 waves publish, khalf=0 waves combine ----
  if (khalf == 1) {
#pragma unroll
    for (int f = 0; f < 4; ++f)
#pragma unroll
      for (int r = 0; r < 4; ++r)
        red[mrow][4 * g + r][16 * f + rl] = acc[f][r];
  }
  __syncthreads();
  if (khalf == 0) {
#pragma unroll
    for (int f = 0; f < 4; ++f)
#pragma unroll
      for (int r = 0; r < 4; ++r) {
        float s = acc[f][r] + red[mrow][4 * g + r][16 * f + rl];
        acc[f][r] = s;
      }
    // publish combined sums for transposed epilogue read
#pragma unroll
    for (int f = 0; f < 4; ++f)
#pragma unroll
      for (int r = 0; r < 4; ++r)
        red[mrow][4 * g + r][16 * f + rl] = acc[f][r];
  }
  __syncthreads();

  if (khalf == 0) {
    // lane-group g handles trees {g, g+4, g+8, g+12}; row rl of this wave's tile
    float o0 = 0.0f, o1 = 0.0f;
#pragma unroll
    for (int jt = 0; jt < 4; ++jt) {
      int t = g + 4 * jt;
      if (t < NT) {
        const float* cf = coef + t * 10;
        float dd[4];
#pragma unroll
        for (int i = 0; i < 4; ++i) {
          float z = red[mrow][rl][4 * t + i] + bias[4 * t + i];
          dd[i] = 1.0f / (1.0f + __expf(-z));
        }
        float s = 1.0f / (4.0f + dd[3] + 1e-8f);
        o0 += s * (cf[0] + dd[0] * cf[2] + dd[1] * cf[4] + dd[2] * cf[6] + dd[3] * cf[8]);
        o1 += s * (cf[1] + dd[0] * cf[3] + dd[1] * cf[5] + dd[2] * cf[7] + dd[3] * cf[9]);
      }
    }
    o0 += __shfl_xor(o0, 16); o0 += __shfl_xor(o0, 32);
    o1 += __shfl_xor(o1, 16); o1 += __shfl_xor(o1, 32);
    if (l < 16) {
      ((float2*)out)[rowTile + rl] = make_float2(o0, o1);
    }
  }
}

// ---------------- launch -----------------------------------------------------
extern "C" void kernel_launch(void* const* d_in, const int* in_sizes, int n_in,
                              void* d_out, int out_size, void* d_ws, size_t ws_size,
                              hipStream_t stream) {
  (void)in_sizes; (void)n_in; (void)out_size; (void)ws_size;
  const float* x  = (const float*)d_in[0];
  const float* tp = (const float*)d_in[1];
  const float* tw = (const float*)d_in[2];
  float* out = (float*)d_out;

  unsigned short* bsp = (unsigned short*)d_ws;                    // 524288 B
  float* bias = (float*)((char*)d_ws + 524288);                   // 256 B
  float* coef = (float*)((char*)d_ws + 524288 + 256);             // 600 B

  prep_split<<<512, 256, 0, stream>>>(tp, tw, bsp, bias, coef);
  tree_fused<<<1024, 256, 0, stream>>>(x, bsp, bias, coef, out);
}

// Round 3
// 56.406 us; speedup vs baseline: 1.4227x; 1.4227x over previous
//
#include <hip/hip_runtime.h>
#include <stdint.h>

#define D_IN    2048
#define NT      15
#define PPT     14359      // 7*(2048+1) + 8*2
#define NVALID  60         // 15 trees * 4 used internal nodes

typedef __bf16   bf16x8 __attribute__((ext_vector_type(8)));
typedef float    f32x4  __attribute__((ext_vector_type(4)));
typedef uint32_t u32x4  __attribute__((ext_vector_type(4)));

#define WAITV8 asm volatile("s_waitcnt vmcnt(8)" ::: "memory")
#define WAITV0 asm volatile("s_waitcnt vmcnt(0)" ::: "memory")
#define WAITL0 asm volatile("s_waitcnt lgkmcnt(0)" ::: "memory")

// ---------------- prep: split W into bf16 hi/lo in MFMA-B fragment order ----
// W[n][k], n = t*4+i (nodes 4..6 never reach the output -> only 60 of 105 cols)
// frag bytes: ((ks*4+f)*2+part)*1024 + lane*16, lane=(n&15)|(((k>>3)&3)<<4)
__global__ __launch_bounds__(256) void prep_split(const float* __restrict__ tp,
                                                  const float* __restrict__ tw,
                                                  unsigned short* __restrict__ bsp,
                                                  float* __restrict__ bias,
                                                  float* __restrict__ coef) {
  int id = blockIdx.x * 256 + threadIdx.x;   // [0, 64*2048)
  int n = id >> 11;
  int k = id & 2047;
  float v = 0.0f;
  if (n < NVALID) {
    int t = n >> 2, i = n & 3;
    v = tp[t * PPT + i * D_IN + k];
  }
  uint32_t u  = __float_as_uint(v);
  uint32_t hm = u & 0xFFFF0000u;             // truncated-bf16 hi (residual catches the rest)
  float    lo = v - __uint_as_float(hm);
  uint32_t lu = __float_as_uint(lo);
  int ks = k >> 5, f = n >> 4;
  int lane = (n & 15) | (((k >> 3) & 3) << 4);
  int j = k & 7;
  size_t base = ((size_t)(ks * 4 + f) * 2) * 512 + (size_t)lane * 8 + j;
  bsp[base]       = (unsigned short)(u  >> 16);   // part 0 = hi
  bsp[base + 512] = (unsigned short)(lu >> 16);   // part 1 = lo

  if (blockIdx.x == 0) {
    int tid = threadIdx.x;
    if (tid < 64) {
      float b = 0.0f;
      if (tid < NVALID) { int t = tid >> 2, i = tid & 3; b = tp[t * PPT + 14336 + i]; }
      bias[tid] = b;
    } else if (tid < 64 + NT) {
      int t = tid - 64;
      const float* ll = tp + t * PPT + 14343;  // leaf_logits [8][2]
      float d0[8], d1[8];
#pragma unroll
      for (int le = 0; le < 8; ++le) {
        float aa = ll[2 * le], bb = ll[2 * le + 1];
        float m = fmaxf(aa, bb);
        float e0 = __expf(aa - m), e1 = __expf(bb - m);
        float inv = 1.0f / (e0 + e1);
        d0[le] = e0 * inv; d1[le] = e1 * inv;
      }
      float w = tw[t];
      float* c = coef + t * 10;
      c[0] = w * (d0[0] + d0[2] + d0[4] + d0[6]);
      c[1] = w * (d1[0] + d1[2] + d1[4] + d1[6]);
      c[2] = w * (d0[1] - d0[2]);
      c[3] = w * (d1[1] - d1[2]);
      c[4] = w * (d0[3] - d0[4]);
      c[5] = w * (d1[3] - d1[4]);
      c[6] = w * (d0[5] - d0[6]);
      c[7] = w * (d1[5] - d1[6]);
      c[8] = w * d0[7];
      c[9] = w * d1[7];
    }
  }
}

// ---------------- asm / builtin helpers --------------------------------------
__device__ __forceinline__ f32x4 gload4(const float* p) {
  f32x4 r;
  asm volatile("global_load_dwordx4 %0, %1, off" : "=v"(r) : "v"(p) : "memory");
  return r;
}
__device__ __forceinline__ u32x4 dsread16(uint32_t addr) {
  u32x4 r;
  asm volatile("ds_read_b128 %0, %1" : "=v"(r) : "v"(addr) : "memory");
  return r;
}
__device__ __forceinline__ void stage16(const void* g, void* l) {
  __builtin_amdgcn_global_load_lds(
      (const __attribute__((address_space(1))) void*)g,
      (__attribute__((address_space(3))) void*)l, 16, 0, 0);
}

#define CVT_PAIR(P, Q, HW, LW) do {                                   \
    uint32_t _up = __float_as_uint(P), _uq = __float_as_uint(Q);      \
    uint32_t _mp = _up & 0xFFFF0000u, _mq = _uq & 0xFFFF0000u;        \
    (HW) = (_up >> 16) | _mq;                                         \
    float _lp = (P) - __uint_as_float(_mp);                           \
    float _lq = (Q) - __uint_as_float(_mq);                           \
    (LW) = (__float_as_uint(_lp) >> 16) |                             \
           (__float_as_uint(_lq) & 0xFFFF0000u);                      \
  } while (0)

__device__ __forceinline__ void cvt_hilo(const f32x4 A, const f32x4 B,
                                         bf16x8& hi, bf16x8& lo) {
  u32x4 hw, lw;
  CVT_PAIR(A[0], A[1], hw[0], lw[0]);
  CVT_PAIR(A[2], A[3], hw[1], lw[1]);
  CVT_PAIR(B[0], B[1], hw[2], lw[2]);
  CVT_PAIR(B[2], B[3], hw[3], lw[3]);
  hi = __builtin_bit_cast(bf16x8, hw);
  lo = __builtin_bit_cast(bf16x8, lw);
}

// Main loop iteration. Protocol (counted vmcnt, one barrier/iter, 3 LDS bufs):
//   top: vmcnt(8) [B(t),A(t) landed; B(t+1),A(t+1) stay in flight] ; s_barrier
//   ds_read 16 B-frags of buf[t%3]; cvt A(t)
//   lgkmcnt(0)  -> my reads done BEFORE next barrier => restage of (t+2)%3 safe
//   issue STAGE B(t+2)->buf[(t+2)%3] + A(t+2) loads (8 vmem ops)
//   24 MFMA
#define ITERATION(tt, BUF, RC, WAIT8, ISSUE)                                   \
  {                                                                            \
    if (WAIT8) { WAITV8; } else { WAITV0; }                                    \
    __builtin_amdgcn_sched_barrier(0);                                         \
    __builtin_amdgcn_s_barrier();                                              \
    const uint32_t bb = sbase + (BUF) * 16384 + l16;                           \
    u32x4 bf[16];                                                              \
    _Pragma("unroll")                                                          \
    for (int h = 0; h < 2; ++h)                                                \
      _Pragma("unroll")                                                        \
      for (int f = 0; f < 4; ++f)                                              \
        _Pragma("unroll")                                                      \
        for (int p2 = 0; p2 < 2; ++p2)                                         \
          bf[h * 8 + f * 2 + p2] = dsread16(bb + h * 8192 + f * 2048 + p2 * 1024); \
    bf16x8 ah0, al0, ah1, al1;                                                 \
    cvt_hilo(RC[0], RC[1], ah0, al0);                                          \
    cvt_hilo(RC[2], RC[3], ah1, al1);                                          \
    WAITL0;                                                                    \
    __builtin_amdgcn_sched_barrier(0);                                         \
    if (ISSUE) {                                                               \
      const int t2 = (tt) + 2;                                                 \
      const char* gsrc = bspb + (size_t)t2 * 16384 + w4096l16;                 \
      char* ldst = sBgen + (((BUF) + 2) % 3) * 16384 + w4096;                  \
      _Pragma("unroll")                                                        \
      for (int q = 0; q < 4; ++q) stage16(gsrc + q * 1024, ldst + q * 1024);   \
      const float* ap = xbase + t2 * 64;                                       \
      RC[0] = gload4(ap);      RC[1] = gload4(ap + 4);                         \
      RC[2] = gload4(ap + 32); RC[3] = gload4(ap + 36);                        \
    }                                                                          \
    _Pragma("unroll")                                                          \
    for (int f = 0; f < 4; ++f) {                                              \
      bf16x8 bh = __builtin_bit_cast(bf16x8, bf[f * 2]);                       \
      bf16x8 bl = __builtin_bit_cast(bf16x8, bf[f * 2 + 1]);                   \
      acc[f] = __builtin_amdgcn_mfma_f32_16x16x32_bf16(ah0, bh, acc[f], 0,0,0);\
      acc[f] = __builtin_amdgcn_mfma_f32_16x16x32_bf16(al0, bh, acc[f], 0,0,0);\
      acc[f] = __builtin_amdgcn_mfma_f32_16x16x32_bf16(ah0, bl, acc[f], 0,0,0);\
    }                                                                          \
    _Pragma("unroll")                                                          \
    for (int f = 0; f < 4; ++f) {                                              \
      bf16x8 bh = __builtin_bit_cast(bf16x8, bf[8 + f * 2]);                   \
      bf16x8 bl = __builtin_bit_cast(bf16x8, bf[8 + f * 2 + 1]);               \
      acc[f] = __builtin_amdgcn_mfma_f32_16x16x32_bf16(ah1, bh, acc[f], 0,0,0);\
      acc[f] = __builtin_amdgcn_mfma_f32_16x16x32_bf16(al1, bh, acc[f], 0,0,0);\
      acc[f] = __builtin_amdgcn_mfma_f32_16x16x32_bf16(ah1, bl, acc[f], 0,0,0);\
    }                                                                          \
  }

__global__ __launch_bounds__(256) void tree_fused(
    const float* __restrict__ x,
    const unsigned short* __restrict__ bsp,
    const float* __restrict__ bias,
    const float* __restrict__ coef,
    float* __restrict__ out)
{
  __shared__ __align__(1024) unsigned char sB[3 * 16384];   // B hi/lo triple buffer
  __shared__ float strips[4][16][65];                       // per-wave epilogue strip

  const int tid = threadIdx.x;
  const int w   = tid >> 6;        // wave 0..3
  const int l   = tid & 63;
  const int rl  = l & 15;
  const int g   = l >> 4;
  const int l16 = l * 16;
  const int w4096 = w * 4096;
  const int w4096l16 = w4096 + l16;

  const int rowTile = blockIdx.x * 64 + w * 16;
  const float* xbase = x + (size_t)(rowTile + rl) * D_IN + g * 8;
  const char* bspb = (const char*)bsp;
  char* sBgen = (char*)&sB[0];
  const uint32_t sbase = (uint32_t)(uintptr_t)sBgen;

  f32x4 acc[4] = {};
  f32x4 rA[4], rB[4];

  // prologue: issue B(0),A(0),B(1),A(1)  -> 16 outstanding vmem ops
  {
    const char* g0 = bspb + w4096l16;
    char* d0 = sBgen + w4096;
#pragma unroll
    for (int q = 0; q < 4; ++q) stage16(g0 + q * 1024, d0 + q * 1024);
    const float* ap = xbase;
    rA[0] = gload4(ap);      rA[1] = gload4(ap + 4);
    rA[2] = gload4(ap + 32); rA[3] = gload4(ap + 36);
    const char* g1 = bspb + 16384 + w4096l16;
    char* d1 = sBgen + 16384 + w4096;
#pragma unroll
    for (int q = 0; q < 4; ++q) stage16(g1 + q * 1024, d1 + q * 1024);
    const float* ap1 = xbase + 64;
    rB[0] = gload4(ap1);      rB[1] = gload4(ap1 + 4);
    rB[2] = gload4(ap1 + 32); rB[3] = gload4(ap1 + 36);
  }

  // main loop: period-6 pattern (buffer %3, A-reg parity %2), 30 iters
  for (int tb = 0; tb < 30; tb += 6) {
    ITERATION(tb + 0, 0, rA, true, true);
    ITERATION(tb + 1, 1, rB, true, true);
    ITERATION(tb + 2, 2, rA, true, true);
    ITERATION(tb + 3, 0, rB, true, true);
    ITERATION(tb + 4, 1, rA, true, true);
    ITERATION(tb + 5, 2, rB, true, true);
  }
  // tail: t=30 (buf 0, rA, wait 8, no issue), t=31 (buf 1, rB, wait 0, no issue)
  ITERATION(30, 0, rA, true, false);
  ITERATION(31, 1, rB, false, false);

  // epilogue: dump C to own wave's strip (same-wave use only)
#pragma unroll
  for (int f = 0; f < 4; ++f)
#pragma unroll
    for (int r = 0; r < 4; ++r)
      strips[w][4 * g + r][16 * f + rl] = acc[f][r];
  WAITL0;

  // lane-group g handles trees {g, g+4, g+8, g+12}; row = rl of this wave's tile
  float o0 = 0.0f, o1 = 0.0f;
#pragma unroll
  for (int jt = 0; jt < 4; ++jt) {
    int t = g + 4 * jt;
    if (t < NT) {
      const float* cf = coef + t * 10;
      float dd[4];
#pragma unroll
      for (int i = 0; i < 4; ++i) {
        float z = strips[w][rl][4 * t + i] + bias[4 * t + i];
        dd[i] = 1.0f / (1.0f + __expf(-z));
      }
      float s = 1.0f / (4.0f + dd[3] + 1e-8f);
      o0 += s * (cf[0] + dd[0] * cf[2] + dd[1] * cf[4] + dd[2] * cf[6] + dd[3] * cf[8]);
      o1 += s * (cf[1] + dd[0] * cf[3] + dd[1] * cf[5] + dd[2] * cf[7] + dd[3] * cf[9]);
    }
  }
  o0 += __shfl_xor(o0, 16); o0 += __shfl_xor(o0, 32);
  o1 += __shfl_xor(o1, 16); o1 += __shfl_xor(o1, 32);
  if (l < 16) {
    ((float2*)out)[rowTile + rl] = make_float2(o0, o1);
  }
}

// ---------------- launch -----------------------------------------------------
extern "C" void kernel_launch(void* const* d_in, const int* in_sizes, int n_in,
                              void* d_out, int out_size, void* d_ws, size_t ws_size,
                              hipStream_t stream) {
  (void)in_sizes; (void)n_in; (void)out_size; (void)ws_size;
  const float* x  = (const float*)d_in[0];
  const float* tp = (const float*)d_in[1];
  const float* tw = (const float*)d_in[2];
  float* out = (float*)d_out;

  unsigned short* bsp = (unsigned short*)d_ws;                    // 524288 B
  float* bias = (float*)((char*)d_ws + 524288);                   // 256 B
  float* coef = (float*)((char*)d_ws + 524288 + 256);             // 600 B

  prep_split<<<512, 256, 0, stream>>>(tp, tw, bsp, bias, coef);
  tree_fused<<<512, 256, 0, stream>>>(x, bsp, bias, coef, out);
}